// Round 4
// baseline (63.284 us; speedup 1.0000x reference)
//
#include <hip/hip_runtime.h>
#include <math.h>

// x = (8, 3, 1024, 1024) f32, out = (8, 3, 1024, 1024) f32
constexpr int H = 1024, W = 1024, B = 8;
constexpr int NPIX = H * W;
constexpr int ROWS = 4;                 // output rows per stage-1 block
constexpr int RG   = H / ROWS;          // 256 row-groups per image

__device__ __forceinline__ float grayat(const float* __restrict__ xb, int r, int c) {
    const float* p = xb + (size_t)r * W + c;
    return 0.3f * p[0] + 0.59f * p[NPIX] + 0.11f * p[2 * NPIX];
}

// Stage 1: block = 4 rows of one image (256 threads x 4 cols).
// 18 independent float4 loads/thread (6 input rows x 3 channels), gray via FMA,
// horizontal neighbors via wave shuffle (edge lanes patched from pre-issued scalar
// loads), 3x3 weighted stencil, un-normalized t -> out channel 0, block-reduce
// sum/sumsq -> one fp32 partial pair per block (no atomics).
__global__ __launch_bounds__(256, 2)
void ltpe_stage1(const float* __restrict__ x, float* __restrict__ out,
                 float2* __restrict__ part)
{
    const int b    = blockIdx.y;
    const int r0   = blockIdx.x * ROWS;
    const int tid  = threadIdx.x;
    const int c    = tid << 2;
    const int lane = tid & 63;
    const float* xb = x + (size_t)b * 3 * NPIX;

    // All 18 main loads issued up front, fully independent.
    float4 q[6][3];
    #pragma unroll
    for (int i = 0; i < 6; ++i) {
        const int rr = r0 - 1 + i;
        float4 z = {0.f, 0.f, 0.f, 0.f};
        q[i][0] = z; q[i][1] = z; q[i][2] = z;
        if ((unsigned)rr < (unsigned)H) {
            const float* p = xb + (size_t)rr * W + c;
            q[i][0] = *reinterpret_cast<const float4*>(p);
            q[i][1] = *reinterpret_cast<const float4*>(p + NPIX);
            q[i][2] = *reinterpret_cast<const float4*>(p + 2 * NPIX);
        }
    }
    // Wave-edge patch loads (lanes 0 / 63 only), issued before the shuffles.
    float pl[6], pr[6];
    #pragma unroll
    for (int i = 0; i < 6; ++i) { pl[i] = 0.f; pr[i] = 0.f; }
    if (lane == 0 && c > 0) {
        #pragma unroll
        for (int i = 0; i < 6; ++i) {
            const int rr = r0 - 1 + i;
            if ((unsigned)rr < (unsigned)H) pl[i] = grayat(xb, rr, c - 1);
        }
    }
    if (lane == 63 && c + 4 < W) {
        #pragma unroll
        for (int i = 0; i < 6; ++i) {
            const int rr = r0 - 1 + i;
            if ((unsigned)rr < (unsigned)H) pr[i] = grayat(xb, rr, c + 4);
        }
    }

    // Gray rows, 6-wide: [0] = col c-1, [1..4] = c..c+3, [5] = c+4.
    float g[6][6];
    #pragma unroll
    for (int i = 0; i < 6; ++i) {
        const float4 a = q[i][0], d = q[i][1], e = q[i][2];
        g[i][1] = 0.3f * a.x + 0.59f * d.x + 0.11f * e.x;
        g[i][2] = 0.3f * a.y + 0.59f * d.y + 0.11f * e.y;
        g[i][3] = 0.3f * a.z + 0.59f * d.z + 0.11f * e.z;
        g[i][4] = 0.3f * a.w + 0.59f * d.w + 0.11f * e.w;
        float l  = __shfl_up(g[i][4], 1);
        float rt = __shfl_down(g[i][1], 1);
        if (lane == 0)  l  = pl[i];
        if (lane == 63) rt = pr[i];
        g[i][0] = l; g[i][5] = rt;
    }

    // OFFSETS j: (0,-1)(1,-1)(1,0)(1,1)(0,1)(-1,1)(-1,0)(-1,-1), w_j = 2^j/255.
    // sum_j w_j == 1  =>  t = 0.5*(g+1) - 0.5 * sum_j w_j * nb_j
    constexpr float w0 = 1.f/255.f,  w1 = 2.f/255.f,  w2 = 4.f/255.f,  w3 = 8.f/255.f,
                    w4 = 16.f/255.f, w5 = 32.f/255.f, w6 = 64.f/255.f, w7 = 128.f/255.f;
    float s = 0.f, ss = 0.f;
    float* ob = out + (size_t)b * 3 * NPIX + (size_t)r0 * W + c;
    #pragma unroll
    for (int rr = 0; rr < ROWS; ++rr) {
        const float (&up)[6] = g[rr];
        const float (&mi)[6] = g[rr + 1];
        const float (&dn)[6] = g[rr + 2];
        float tv[4];
        #pragma unroll
        for (int kk = 0; kk < 4; ++kk) {
            float sv = w0 * mi[kk];             // mid[-1]
            sv = fmaf(w1, dn[kk],     sv);      // dn[-1]
            sv = fmaf(w2, dn[kk + 1], sv);      // dn[0]
            sv = fmaf(w3, dn[kk + 2], sv);      // dn[+1]
            sv = fmaf(w4, mi[kk + 2], sv);      // mid[+1]
            sv = fmaf(w5, up[kk + 2], sv);      // up[+1]
            sv = fmaf(w6, up[kk + 1], sv);      // up[0]
            sv = fmaf(w7, up[kk],     sv);      // up[-1]
            tv[kk] = 0.5f * mi[kk + 1] + 0.5f - 0.5f * sv;
            s += tv[kk];
            ss = fmaf(tv[kk], tv[kk], ss);
        }
        float4 t4 = {tv[0], tv[1], tv[2], tv[3]};
        *reinterpret_cast<float4*>(ob + (size_t)rr * W) = t4;
    }

    // Block reduce -> one fp32 partial pair per block.
    #pragma unroll
    for (int off = 32; off >= 1; off >>= 1) {
        s  += __shfl_down(s, off);
        ss += __shfl_down(ss, off);
    }
    __shared__ float2 wred[4];
    if (lane == 0) wred[tid >> 6] = make_float2(s, ss);
    __syncthreads();
    if (tid == 0) {
        float2 a0 = wred[0], a1 = wred[1], a2 = wred[2], a3 = wred[3];
        part[(size_t)b * RG + blockIdx.x] =
            make_float2(a0.x + a1.x + a2.x + a3.x, a0.y + a1.y + a2.y + a3.y);
    }
}

// Stage 2: per-image reduce of 256 fp32 partials in double -> mean, rstd.
__global__ __launch_bounds__(256)
void ltpe_stage2(const float2* __restrict__ part, float* __restrict__ scal)
{
    const int b = blockIdx.x;
    const int tid = threadIdx.x;
    const float2 p = part[(size_t)b * RG + tid];
    double s = (double)p.x, ss = (double)p.y;
    #pragma unroll
    for (int off = 32; off >= 1; off >>= 1) {
        s  += __shfl_down(s, off);
        ss += __shfl_down(ss, off);
    }
    __shared__ double red[8];
    const int lane = tid & 63, wv = tid >> 6;
    if (lane == 0) { red[wv] = s; red[4 + wv] = ss; }
    __syncthreads();
    if (tid == 0) {
        const double S  = red[0] + red[1] + red[2] + red[3];
        const double SS = red[4] + red[5] + red[6] + red[7];
        const double n    = (double)NPIX;
        const double mean = S / n;
        const double var  = SS / n - mean * mean;
        scal[2 * b]     = (float)mean;
        scal[2 * b + 1] = (float)(1.0 / sqrt(var + 1e-5));
    }
}

// Stage 3: normalize channel-0 t in place and replicate to channels 1,2 (float4).
__global__ __launch_bounds__(256)
void ltpe_stage3(float* __restrict__ out, const float* __restrict__ scal)
{
    const int b = blockIdx.y;
    const float mean = scal[2 * b];
    const float rstd = scal[2 * b + 1];
    const size_t base = (size_t)b * 3 * NPIX +
                        ((size_t)blockIdx.x * 256 + threadIdx.x) * 4;
    const float4 t4 = *reinterpret_cast<const float4*>(out + base);
    float4 y;
    y.x = (t4.x - mean) * rstd;
    y.y = (t4.y - mean) * rstd;
    y.z = (t4.z - mean) * rstd;
    y.w = (t4.w - mean) * rstd;
    *reinterpret_cast<float4*>(out + base)            = y;
    *reinterpret_cast<float4*>(out + base + NPIX)     = y;
    *reinterpret_cast<float4*>(out + base + 2 * NPIX) = y;
}

extern "C" void kernel_launch(void* const* d_in, const int* in_sizes, int n_in,
                              void* d_out, int out_size, void* d_ws, size_t ws_size,
                              hipStream_t stream)
{
    const float* x = (const float*)d_in[0];
    float* out = (float*)d_out;
    float2* part = (float2*)d_ws;                   // B*RG = 2048 float2 = 16 KiB
    float* scal  = (float*)((char*)d_ws + 16384);   // 16 floats: mean/rstd pairs

    ltpe_stage1<<<dim3(RG, B), 256, 0, stream>>>(x, out, part);
    ltpe_stage2<<<B, 256, 0, stream>>>(part, scal);
    ltpe_stage3<<<dim3(NPIX / 1024, B), 256, 0, stream>>>(out, scal);
}

// Round 5
// 54.359 us; speedup vs baseline: 1.1642x; 1.1642x over previous
//
#include <hip/hip_runtime.h>
#include <math.h>

// x = (8, 3, 1024, 1024) f32, out = (8, 3, 1024, 1024) f32
constexpr int H = 1024, W = 1024, B = 8;
constexpr int NPIX = H * W;

__device__ __forceinline__ float grayat(const float* __restrict__ xb, int r, int c) {
    const float* p = xb + (size_t)r * W + c;
    return 0.3f * p[0] + 0.59f * p[NPIX] + 0.11f * p[2 * NPIX];
}

// Stage 1 (round-2 proven form): one block = one row of one image (256 thr x 4 cols).
// 9 independent float4 loads -> 3 gray quads, horizontal neighbors via wave shuffle,
// 3x3 weighted stencil, un-normalized t -> out channel 0, block partial -> part[].
__global__ __launch_bounds__(256)
void ltpe_stage1(const float* __restrict__ x, float* __restrict__ out,
                 float2* __restrict__ part)
{
    const int b    = blockIdx.y;
    const int k    = blockIdx.x;                  // dispatch row index
    const int r    = ((k & 7) << 7) | (k >> 3);   // XCD-chunked bijective swizzle (8 x 128)
    const int tid  = threadIdx.x;
    const int c    = tid << 2;                    // first output column
    const int lane = tid & 63;

    const float* xb = x + (size_t)b * 3 * NPIX;

    // 3 rows x 3 channels, all loads independent.
    float4 g[3];
    #pragma unroll
    for (int dr = 0; dr < 3; ++dr) {
        const int rr = r + dr - 1;
        float4 q0 = {0.f,0.f,0.f,0.f}, q1 = q0, q2 = q0;
        if ((unsigned)rr < (unsigned)H) {
            const float* p = xb + (size_t)rr * W + c;
            q0 = *reinterpret_cast<const float4*>(p);
            q1 = *reinterpret_cast<const float4*>(p + NPIX);
            q2 = *reinterpret_cast<const float4*>(p + 2 * NPIX);
        }
        g[dr].x = 0.3f * q0.x + 0.59f * q1.x + 0.11f * q2.x;
        g[dr].y = 0.3f * q0.y + 0.59f * q1.y + 0.11f * q2.y;
        g[dr].z = 0.3f * q0.z + 0.59f * q1.z + 0.11f * q2.z;
        g[dr].w = 0.3f * q0.w + 0.59f * q1.w + 0.11f * q2.w;
    }

    // Horizontal neighbors from adjacent lanes; wave-edge lanes patch via scalar loads.
    float gl[3], gr[3];
    #pragma unroll
    for (int dr = 0; dr < 3; ++dr) {
        gl[dr] = __shfl_up(g[dr].w, 1);
        gr[dr] = __shfl_down(g[dr].x, 1);
    }
    if (lane == 0) {
        #pragma unroll
        for (int dr = 0; dr < 3; ++dr) {
            const int rr = r + dr - 1;
            gl[dr] = (c > 0 && (unsigned)rr < (unsigned)H) ? grayat(xb, rr, c - 1) : 0.f;
        }
    }
    if (lane == 63) {
        #pragma unroll
        for (int dr = 0; dr < 3; ++dr) {
            const int rr = r + dr - 1;
            gr[dr] = (c + 4 < W && (unsigned)rr < (unsigned)H) ? grayat(xb, rr, c + 4) : 0.f;
        }
    }

    // 6-wide gray rows: index 0 is col c-1, 1..4 are c..c+3, 5 is c+4.
    float up[6], mi[6], dn[6];
    up[0]=gl[0]; up[1]=g[0].x; up[2]=g[0].y; up[3]=g[0].z; up[4]=g[0].w; up[5]=gr[0];
    mi[0]=gl[1]; mi[1]=g[1].x; mi[2]=g[1].y; mi[3]=g[1].z; mi[4]=g[1].w; mi[5]=gr[1];
    dn[0]=gl[2]; dn[1]=g[2].x; dn[2]=g[2].y; dn[3]=g[2].z; dn[4]=g[2].w; dn[5]=gr[2];

    // OFFSETS j: (0,-1)(1,-1)(1,0)(1,1)(0,1)(-1,1)(-1,0)(-1,-1), w_j = 2^j/255, sum w == 1
    // => t = 0.5*(g+1) - 0.5 * sum_j w_j * nb_j
    constexpr float w0 = 1.f/255.f,  w1 = 2.f/255.f,  w2 = 4.f/255.f,  w3 = 8.f/255.f,
                    w4 = 16.f/255.f, w5 = 32.f/255.f, w6 = 64.f/255.f, w7 = 128.f/255.f;
    float tv[4];
    #pragma unroll
    for (int kk = 0; kk < 4; ++kk) {
        float s = w0 * mi[kk];              // mid[-1]
        s = fmaf(w1, dn[kk],     s);        // dn[-1]
        s = fmaf(w2, dn[kk + 1], s);        // dn[0]
        s = fmaf(w3, dn[kk + 2], s);        // dn[+1]
        s = fmaf(w4, mi[kk + 2], s);        // mid[+1]
        s = fmaf(w5, up[kk + 2], s);        // up[+1]
        s = fmaf(w6, up[kk + 1], s);        // up[0]
        s = fmaf(w7, up[kk],     s);        // up[-1]
        tv[kk] = 0.5f * mi[kk + 1] + 0.5f - 0.5f * s;
    }

    float4 t4 = {tv[0], tv[1], tv[2], tv[3]};
    *reinterpret_cast<float4*>(out + (size_t)b * 3 * NPIX + (size_t)r * W + c) = t4;

    // Block reduction: wave shuffle -> LDS -> one fp32 partial pair per block.
    float s  = tv[0] + tv[1] + tv[2] + tv[3];
    float ss = tv[0]*tv[0] + tv[1]*tv[1] + tv[2]*tv[2] + tv[3]*tv[3];
    #pragma unroll
    for (int off = 32; off >= 1; off >>= 1) {
        s  += __shfl_down(s, off);
        ss += __shfl_down(ss, off);
    }
    __shared__ float2 wred[4];
    if (lane == 0) wred[tid >> 6] = make_float2(s, ss);
    __syncthreads();
    if (tid == 0) {
        float2 a0 = wred[0], a1 = wred[1], a2 = wred[2], a3 = wred[3];
        part[(size_t)b * H + k] = make_float2(a0.x + a1.x + a2.x + a3.x,
                                              a0.y + a1.y + a2.y + a3.y);
    }
}

// Stage B (fused stage2+stage3): each block redundantly reduces its image's 1024
// partial pairs (double precision -> bit-identical scalars across blocks), then
// normalizes one t-row and writes the 3 replicated channels (float4).
__global__ __launch_bounds__(256)
void ltpe_stageB(float* __restrict__ out, const float2* __restrict__ part)
{
    const int b   = blockIdx.y;
    const int r   = blockIdx.x;
    const int tid = threadIdx.x;
    const int lane = tid & 63;

    // Redundant per-block reduce of 1024 float2 partials (8 KB, L2-resident).
    const float4* pp = reinterpret_cast<const float4*>(part + (size_t)b * H);
    const float4 u = pp[tid * 2];
    const float4 v = pp[tid * 2 + 1];
    double s  = (double)u.x + (double)u.z + (double)v.x + (double)v.z;
    double ss = (double)u.y + (double)u.w + (double)v.y + (double)v.w;
    #pragma unroll
    for (int off = 32; off >= 1; off >>= 1) {
        s  += __shfl_down(s, off);
        ss += __shfl_down(ss, off);
    }
    __shared__ double red[8];
    __shared__ float2 mv;
    const int wv = tid >> 6;
    if (lane == 0) { red[wv] = s; red[4 + wv] = ss; }
    __syncthreads();
    if (tid == 0) {
        const double S  = red[0] + red[1] + red[2] + red[3];
        const double SS = red[4] + red[5] + red[6] + red[7];
        const double n    = (double)NPIX;
        const double mean = S / n;
        const double var  = SS / n - mean * mean;
        mv = make_float2((float)mean, (float)(1.0 / sqrt(var + 1e-5)));
    }
    __syncthreads();
    const float mean = mv.x, rstd = mv.y;

    // Normalize this row's t (channel 0, in place) and replicate to channels 1,2.
    const size_t base = (size_t)b * 3 * NPIX + (size_t)r * W + (tid << 2);
    const float4 t4 = *reinterpret_cast<const float4*>(out + base);
    float4 y;
    y.x = (t4.x - mean) * rstd;
    y.y = (t4.y - mean) * rstd;
    y.z = (t4.z - mean) * rstd;
    y.w = (t4.w - mean) * rstd;
    *reinterpret_cast<float4*>(out + base)            = y;
    *reinterpret_cast<float4*>(out + base + NPIX)     = y;
    *reinterpret_cast<float4*>(out + base + 2 * NPIX) = y;
}

extern "C" void kernel_launch(void* const* d_in, const int* in_sizes, int n_in,
                              void* d_out, int out_size, void* d_ws, size_t ws_size,
                              hipStream_t stream)
{
    const float* x = (const float*)d_in[0];
    float* out = (float*)d_out;
    float2* part = (float2*)d_ws;                   // 8192 float2 = 64 KiB

    ltpe_stage1<<<dim3(H, B), 256, 0, stream>>>(x, out, part);
    ltpe_stageB<<<dim3(H, B), 256, 0, stream>>>(out, part);
}

// Round 6
// 51.652 us; speedup vs baseline: 1.2252x; 1.0524x over previous
//
#include <hip/hip_runtime.h>
#include <math.h>

// x = (8, 3, 1024, 1024) f32, out = (8, 3, 1024, 1024) f32
constexpr int H = 1024, W = 1024, B = 8;
constexpr int NPIX = H * W;
constexpr int ROWS = 2;                 // output rows per stage-1 block
constexpr int RG   = H / ROWS;          // 512 row-groups per image

// Direct global->LDS load, 16 B per lane (m97 pattern): LDS dest is wave-uniform
// base + lane*16; global src is per-lane. Data never touches VGPRs.
__device__ __forceinline__ void gload_lds16(const float* g, float* l) {
    __builtin_amdgcn_global_load_lds(
        (const __attribute__((address_space(1))) void*)g,
        (__attribute__((address_space(3))) void*)l, 16, 0, 0);
}

// Stage 1: block = 2 rows of one image (256 threads x 4 cols).
// Stage 4 input rows x 3 channels (48 KB) into LDS via global_load_lds_dwordx4
// (12 per thread, VGPR-free => deep in-flight queue), then gray+stencil from LDS
// with conflict-free ds_read_b128. Un-normalized t -> out channel 0; block
// partial sum/sumsq -> part[] (no atomics).
__global__ __launch_bounds__(256)
void ltpe_stage1(const float* __restrict__ x, float* __restrict__ out,
                 float2* __restrict__ part)
{
    __shared__ float lds[4][3][W];                // 48 KiB -> 3 blocks/CU
    const int b   = blockIdx.y;
    const int k   = blockIdx.x;                   // [0, 512)
    const int kg  = ((k & 7) << 6) | (k >> 3);    // XCD-chunked bijective swizzle (8 x 64)
    const int r0  = kg * ROWS;
    const int tid = threadIdx.x;
    const int w   = tid >> 6;                     // wave id (stages one row-quarter)
    const int l   = tid & 63;
    const int c   = tid << 2;                     // this thread's column quad
    const float* xb = x + (size_t)b * 3 * NPIX;

    // ---- staging: rows r0-1 .. r0+2, all 3 channels ----
    #pragma unroll
    for (int s = 0; s < 4; ++s) {
        const int rr = r0 - 1 + s;
        if ((unsigned)rr < (unsigned)H) {         // uniform per block
            #pragma unroll
            for (int ch = 0; ch < 3; ++ch) {
                const float* gp = xb + (size_t)ch * NPIX + (size_t)rr * W + (w << 8) + (l << 2);
                gload_lds16(gp, &lds[s][ch][w << 8]);
            }
        } else {                                  // zero-pad row (image top/bottom)
            const float4 z = make_float4(0.f, 0.f, 0.f, 0.f);
            #pragma unroll
            for (int ch = 0; ch < 3; ++ch)
                *reinterpret_cast<float4*>(&lds[s][ch][c]) = z;
        }
    }
    __syncthreads();                              // drains vmcnt + lgkmcnt

    // ---- gray rows, 6-wide: [0] = col c-1, [1..4] = c..c+3, [5] = c+4 ----
    const int ql = (tid == 0)   ? 0   : tid - 1;  // clamped neighbor quads
    const int qr = (tid == 255) ? 255 : tid + 1;
    float g6[4][6];
    #pragma unroll
    for (int s = 0; s < 4; ++s) {
        const float4 o0 = *reinterpret_cast<const float4*>(&lds[s][0][c]);
        const float4 o1 = *reinterpret_cast<const float4*>(&lds[s][1][c]);
        const float4 o2 = *reinterpret_cast<const float4*>(&lds[s][2][c]);
        const float4 l0 = *reinterpret_cast<const float4*>(&lds[s][0][ql << 2]);
        const float4 l1 = *reinterpret_cast<const float4*>(&lds[s][1][ql << 2]);
        const float4 l2 = *reinterpret_cast<const float4*>(&lds[s][2][ql << 2]);
        const float4 rq0 = *reinterpret_cast<const float4*>(&lds[s][0][qr << 2]);
        const float4 rq1 = *reinterpret_cast<const float4*>(&lds[s][1][qr << 2]);
        const float4 rq2 = *reinterpret_cast<const float4*>(&lds[s][2][qr << 2]);
        g6[s][1] = 0.3f * o0.x + 0.59f * o1.x + 0.11f * o2.x;
        g6[s][2] = 0.3f * o0.y + 0.59f * o1.y + 0.11f * o2.y;
        g6[s][3] = 0.3f * o0.z + 0.59f * o1.z + 0.11f * o2.z;
        g6[s][4] = 0.3f * o0.w + 0.59f * o1.w + 0.11f * o2.w;
        g6[s][0] = (tid == 0)   ? 0.f : 0.3f * l0.w  + 0.59f * l1.w  + 0.11f * l2.w;
        g6[s][5] = (tid == 255) ? 0.f : 0.3f * rq0.x + 0.59f * rq1.x + 0.11f * rq2.x;
    }

    // OFFSETS j: (0,-1)(1,-1)(1,0)(1,1)(0,1)(-1,1)(-1,0)(-1,-1), w_j = 2^j/255, sum w == 1
    // => t = 0.5*(g+1) - 0.5 * sum_j w_j * nb_j
    constexpr float w0 = 1.f/255.f,  w1 = 2.f/255.f,  w2 = 4.f/255.f,  w3 = 8.f/255.f,
                    w4 = 16.f/255.f, w5 = 32.f/255.f, w6 = 64.f/255.f, w7 = 128.f/255.f;
    float s = 0.f, ss = 0.f;
    float* ob = out + (size_t)b * 3 * NPIX + (size_t)r0 * W + c;
    #pragma unroll
    for (int rr = 0; rr < ROWS; ++rr) {
        const float (&up)[6] = g6[rr];
        const float (&mi)[6] = g6[rr + 1];
        const float (&dn)[6] = g6[rr + 2];
        float tv[4];
        #pragma unroll
        for (int kk = 0; kk < 4; ++kk) {
            float sv = w0 * mi[kk];             // mid[-1]
            sv = fmaf(w1, dn[kk],     sv);      // dn[-1]
            sv = fmaf(w2, dn[kk + 1], sv);      // dn[0]
            sv = fmaf(w3, dn[kk + 2], sv);      // dn[+1]
            sv = fmaf(w4, mi[kk + 2], sv);      // mid[+1]
            sv = fmaf(w5, up[kk + 2], sv);      // up[+1]
            sv = fmaf(w6, up[kk + 1], sv);      // up[0]
            sv = fmaf(w7, up[kk],     sv);      // up[-1]
            tv[kk] = 0.5f * mi[kk + 1] + 0.5f - 0.5f * sv;
            s += tv[kk];
            ss = fmaf(tv[kk], tv[kk], ss);
        }
        float4 t4 = {tv[0], tv[1], tv[2], tv[3]};
        *reinterpret_cast<float4*>(ob + (size_t)rr * W) = t4;
    }

    // Block reduction -> one fp32 partial pair per block.
    #pragma unroll
    for (int off = 32; off >= 1; off >>= 1) {
        s  += __shfl_down(s, off);
        ss += __shfl_down(ss, off);
    }
    __shared__ float2 wred[4];
    if (l == 0) wred[w] = make_float2(s, ss);
    __syncthreads();
    if (tid == 0) {
        float2 a0 = wred[0], a1 = wred[1], a2 = wred[2], a3 = wred[3];
        part[(size_t)b * RG + kg] = make_float2(a0.x + a1.x + a2.x + a3.x,
                                                a0.y + a1.y + a2.y + a3.y);
    }
}

// Stage B (fused stage2+stage3): each block redundantly reduces its image's 512
// partial pairs (double precision -> bit-identical scalars across blocks), then
// normalizes one t-row and writes the 3 replicated channels (float4).
__global__ __launch_bounds__(256)
void ltpe_stageB(float* __restrict__ out, const float2* __restrict__ part)
{
    const int b    = blockIdx.y;
    const int r    = blockIdx.x;
    const int tid  = threadIdx.x;
    const int lane = tid & 63;

    // 512 float2 partials = 256 float4; one per thread (L2-resident).
    const float4* pp = reinterpret_cast<const float4*>(part + (size_t)b * RG);
    const float4 u = pp[tid];
    double s  = (double)u.x + (double)u.z;
    double ss = (double)u.y + (double)u.w;
    #pragma unroll
    for (int off = 32; off >= 1; off >>= 1) {
        s  += __shfl_down(s, off);
        ss += __shfl_down(ss, off);
    }
    __shared__ double red[8];
    __shared__ float2 mv;
    const int wv = tid >> 6;
    if (lane == 0) { red[wv] = s; red[4 + wv] = ss; }
    __syncthreads();
    if (tid == 0) {
        const double S  = red[0] + red[1] + red[2] + red[3];
        const double SS = red[4] + red[5] + red[6] + red[7];
        const double n    = (double)NPIX;
        const double mean = S / n;
        const double var  = SS / n - mean * mean;
        mv = make_float2((float)mean, (float)(1.0 / sqrt(var + 1e-5)));
    }
    __syncthreads();
    const float mean = mv.x, rstd = mv.y;

    // Normalize this row's t (channel 0, in place) and replicate to channels 1,2.
    const size_t base = (size_t)b * 3 * NPIX + (size_t)r * W + (tid << 2);
    const float4 t4 = *reinterpret_cast<const float4*>(out + base);
    float4 y;
    y.x = (t4.x - mean) * rstd;
    y.y = (t4.y - mean) * rstd;
    y.z = (t4.z - mean) * rstd;
    y.w = (t4.w - mean) * rstd;
    *reinterpret_cast<float4*>(out + base)            = y;
    *reinterpret_cast<float4*>(out + base + NPIX)     = y;
    *reinterpret_cast<float4*>(out + base + 2 * NPIX) = y;
}

extern "C" void kernel_launch(void* const* d_in, const int* in_sizes, int n_in,
                              void* d_out, int out_size, void* d_ws, size_t ws_size,
                              hipStream_t stream)
{
    const float* x = (const float*)d_in[0];
    float* out = (float*)d_out;
    float2* part = (float2*)d_ws;                   // B*RG = 4096 float2 = 32 KiB

    ltpe_stage1<<<dim3(RG, B), 256, 0, stream>>>(x, out, part);
    ltpe_stageB<<<dim3(H, B), 256, 0, stream>>>(out, part);
}

// Round 7
// 51.151 us; speedup vs baseline: 1.2372x; 1.0098x over previous
//
#include <hip/hip_runtime.h>
#include <hip/hip_cooperative_groups.h>
#include <math.h>

namespace cg = cooperative_groups;

// x = (8, 3, 1024, 1024) f32, out = (8, 3, 1024, 1024) f32
constexpr int H = 1024, W = 1024, B = 8;
constexpr int NPIX = H * W;

// ---------- fused cooperative path ----------
constexpr int FROWS = 8;                  // rows per fused block
constexpr int FGRID = B * (H / FROWS);    // 1024 blocks

__device__ __forceinline__ float grayat(const float* __restrict__ xb, int r, int c) {
    const float* p = xb + (size_t)r * W + c;
    return 0.3f * p[0] + 0.59f * p[NPIX] + 0.11f * p[2 * NPIX];
}

// One fused kernel: gray + stencil -> t in REGISTERS (8 float4), per-block partial
// -> part[], grid.sync(), 64-lane butterfly reduce of partials (bit-identical in
// every block), normalize regs, write 3 replicated channels. ~0 LDS => cooperative
// co-residency is not LDS-capped; launch_bounds(256,4) caps VGPR at 128.
__global__ __launch_bounds__(256, 4)
void ltpe_fused(const float* __restrict__ x, float* __restrict__ out,
                float2* __restrict__ part)
{
    const int blk  = blockIdx.x;
    const int b    = blk & 7;             // image pinned to XCD (dispatch round-robin)
    const int g    = blk >> 3;            // row-group 0..127
    const int r0   = g * FROWS;
    const int tid  = threadIdx.x;
    const int c    = tid << 2;
    const int lane = tid & 63;
    const float* xb = x + (size_t)b * 3 * NPIX;

    constexpr float w0 = 1.f/255.f,  w1 = 2.f/255.f,  w2 = 4.f/255.f,  w3 = 8.f/255.f,
                    w4 = 16.f/255.f, w5 = 32.f/255.f, w6 = 64.f/255.f, w7 = 128.f/255.f;

    // Gray row producer: 6-wide (left nb, 4 own, right nb) for input row rr.
    auto grayrow = [&](int rr, float (&dst)[6]) {
        float4 q0 = {0.f,0.f,0.f,0.f}, q1 = q0, q2 = q0;
        const bool rok = (unsigned)rr < (unsigned)H;
        if (rok) {
            const float* p = xb + (size_t)rr * W + c;
            q0 = *reinterpret_cast<const float4*>(p);
            q1 = *reinterpret_cast<const float4*>(p + NPIX);
            q2 = *reinterpret_cast<const float4*>(p + 2 * NPIX);
        }
        float4 gq;
        gq.x = 0.3f * q0.x + 0.59f * q1.x + 0.11f * q2.x;
        gq.y = 0.3f * q0.y + 0.59f * q1.y + 0.11f * q2.y;
        gq.z = 0.3f * q0.z + 0.59f * q1.z + 0.11f * q2.z;
        gq.w = 0.3f * q0.w + 0.59f * q1.w + 0.11f * q2.w;
        float l  = __shfl_up(gq.w, 1);
        float rt = __shfl_down(gq.x, 1);
        if (lane == 0)  l  = (c > 0 && rok)     ? grayat(xb, rr, c - 1) : 0.f;
        if (lane == 63) rt = (c + 4 < W && rok) ? grayat(xb, rr, c + 4) : 0.f;
        dst[0] = l; dst[1] = gq.x; dst[2] = gq.y; dst[3] = gq.z; dst[4] = gq.w; dst[5] = rt;
    };

    float gray[3][6];
    float4 tq[FROWS];                     // un-normalized t, lives in VGPRs
    float s = 0.f, ss = 0.f;

    // Rolling over 10 gray rows (r0-1 .. r0+8); full unroll -> all indices static.
    #pragma unroll
    for (int i = 0; i < FROWS + 2; ++i) {
        grayrow(r0 - 1 + i, gray[i % 3]);
        if (i >= 2) {
            const float (&up)[6] = gray[(i - 2) % 3];
            const float (&mi)[6] = gray[(i - 1) % 3];
            const float (&dn)[6] = gray[i % 3];
            float tv[4];
            #pragma unroll
            for (int kk = 0; kk < 4; ++kk) {
                float sv = w0 * mi[kk];             // mid[-1]
                sv = fmaf(w1, dn[kk],     sv);      // dn[-1]
                sv = fmaf(w2, dn[kk + 1], sv);      // dn[0]
                sv = fmaf(w3, dn[kk + 2], sv);      // dn[+1]
                sv = fmaf(w4, mi[kk + 2], sv);      // mid[+1]
                sv = fmaf(w5, up[kk + 2], sv);      // up[+1]
                sv = fmaf(w6, up[kk + 1], sv);      // up[0]
                sv = fmaf(w7, up[kk],     sv);      // up[-1]
                tv[kk] = 0.5f * mi[kk + 1] + 0.5f - 0.5f * sv;
                s += tv[kk];
                ss = fmaf(tv[kk], tv[kk], ss);
            }
            tq[i - 2] = make_float4(tv[0], tv[1], tv[2], tv[3]);
        }
    }

    // Block reduce -> one fp32 partial pair per block.
    #pragma unroll
    for (int off = 32; off >= 1; off >>= 1) {
        s  += __shfl_down(s, off);
        ss += __shfl_down(ss, off);
    }
    __shared__ float2 wred[4];
    if (lane == 0) wred[tid >> 6] = make_float2(s, ss);
    __syncthreads();
    if (tid == 0) {
        float2 a0 = wred[0], a1 = wred[1], a2 = wred[2], a3 = wred[3];
        part[(size_t)b * 128 + g] = make_float2(a0.x + a1.x + a2.x + a3.x,
                                                a0.y + a1.y + a2.y + a3.y);
    }

    cg::this_grid().sync();

    // Phase B: every wave butterfly-reduces its image's 128 float2 partials
    // (64 float4, one per lane) in double -> identical scalars everywhere.
    const float4* pp = reinterpret_cast<const float4*>(part + (size_t)b * 128);
    const float4 u = pp[lane];
    double ds = (double)u.x + (double)u.z;
    double dss = (double)u.y + (double)u.w;
    #pragma unroll
    for (int off = 1; off <= 32; off <<= 1) {
        ds  += __shfl_xor(ds, off);
        dss += __shfl_xor(dss, off);
    }
    const double n    = (double)NPIX;
    const double dmean = ds / n;
    const double dvar  = dss / n - dmean * dmean;
    const float mean = (float)dmean;
    const float rstd = (float)(1.0 / sqrt(dvar + 1e-5));

    float* ob = out + (size_t)b * 3 * NPIX + (size_t)r0 * W + c;
    #pragma unroll
    for (int rr = 0; rr < FROWS; ++rr) {
        const float4 t4 = tq[rr];
        float4 y;
        y.x = (t4.x - mean) * rstd;
        y.y = (t4.y - mean) * rstd;
        y.z = (t4.z - mean) * rstd;
        y.w = (t4.w - mean) * rstd;
        float* p = ob + (size_t)rr * W;
        *reinterpret_cast<float4*>(p)            = y;
        *reinterpret_cast<float4*>(p + NPIX)     = y;
        *reinterpret_cast<float4*>(p + 2 * NPIX) = y;
    }
}

// ---------- fallback path: proven round-6 two-kernel pipeline ----------
constexpr int ROWS = 2;
constexpr int RG   = H / ROWS;          // 512

__device__ __forceinline__ void gload_lds16(const float* g, float* l) {
    __builtin_amdgcn_global_load_lds(
        (const __attribute__((address_space(1))) void*)g,
        (__attribute__((address_space(3))) void*)l, 16, 0, 0);
}

__global__ __launch_bounds__(256)
void ltpe_stage1(const float* __restrict__ x, float* __restrict__ out,
                 float2* __restrict__ part)
{
    __shared__ float lds[4][3][W];                // 48 KiB -> 3 blocks/CU
    const int b   = blockIdx.y;
    const int k   = blockIdx.x;                   // [0, 512)
    const int kg  = ((k & 7) << 6) | (k >> 3);    // XCD-chunked bijective swizzle (8 x 64)
    const int r0  = kg * ROWS;
    const int tid = threadIdx.x;
    const int w   = tid >> 6;
    const int l   = tid & 63;
    const int c   = tid << 2;
    const float* xb = x + (size_t)b * 3 * NPIX;

    #pragma unroll
    for (int s = 0; s < 4; ++s) {
        const int rr = r0 - 1 + s;
        if ((unsigned)rr < (unsigned)H) {
            #pragma unroll
            for (int ch = 0; ch < 3; ++ch) {
                const float* gp = xb + (size_t)ch * NPIX + (size_t)rr * W + (w << 8) + (l << 2);
                gload_lds16(gp, &lds[s][ch][w << 8]);
            }
        } else {
            const float4 z = make_float4(0.f, 0.f, 0.f, 0.f);
            #pragma unroll
            for (int ch = 0; ch < 3; ++ch)
                *reinterpret_cast<float4*>(&lds[s][ch][c]) = z;
        }
    }
    __syncthreads();

    const int ql = (tid == 0)   ? 0   : tid - 1;
    const int qr = (tid == 255) ? 255 : tid + 1;
    float g6[4][6];
    #pragma unroll
    for (int s = 0; s < 4; ++s) {
        const float4 o0 = *reinterpret_cast<const float4*>(&lds[s][0][c]);
        const float4 o1 = *reinterpret_cast<const float4*>(&lds[s][1][c]);
        const float4 o2 = *reinterpret_cast<const float4*>(&lds[s][2][c]);
        const float4 l0 = *reinterpret_cast<const float4*>(&lds[s][0][ql << 2]);
        const float4 l1 = *reinterpret_cast<const float4*>(&lds[s][1][ql << 2]);
        const float4 l2 = *reinterpret_cast<const float4*>(&lds[s][2][ql << 2]);
        const float4 rq0 = *reinterpret_cast<const float4*>(&lds[s][0][qr << 2]);
        const float4 rq1 = *reinterpret_cast<const float4*>(&lds[s][1][qr << 2]);
        const float4 rq2 = *reinterpret_cast<const float4*>(&lds[s][2][qr << 2]);
        g6[s][1] = 0.3f * o0.x + 0.59f * o1.x + 0.11f * o2.x;
        g6[s][2] = 0.3f * o0.y + 0.59f * o1.y + 0.11f * o2.y;
        g6[s][3] = 0.3f * o0.z + 0.59f * o1.z + 0.11f * o2.z;
        g6[s][4] = 0.3f * o0.w + 0.59f * o1.w + 0.11f * o2.w;
        g6[s][0] = (tid == 0)   ? 0.f : 0.3f * l0.w  + 0.59f * l1.w  + 0.11f * l2.w;
        g6[s][5] = (tid == 255) ? 0.f : 0.3f * rq0.x + 0.59f * rq1.x + 0.11f * rq2.x;
    }

    constexpr float w0 = 1.f/255.f,  w1 = 2.f/255.f,  w2 = 4.f/255.f,  w3 = 8.f/255.f,
                    w4 = 16.f/255.f, w5 = 32.f/255.f, w6 = 64.f/255.f, w7 = 128.f/255.f;
    float s = 0.f, ss = 0.f;
    float* ob = out + (size_t)b * 3 * NPIX + (size_t)r0 * W + c;
    #pragma unroll
    for (int rr = 0; rr < ROWS; ++rr) {
        const float (&up)[6] = g6[rr];
        const float (&mi)[6] = g6[rr + 1];
        const float (&dn)[6] = g6[rr + 2];
        float tv[4];
        #pragma unroll
        for (int kk = 0; kk < 4; ++kk) {
            float sv = w0 * mi[kk];
            sv = fmaf(w1, dn[kk],     sv);
            sv = fmaf(w2, dn[kk + 1], sv);
            sv = fmaf(w3, dn[kk + 2], sv);
            sv = fmaf(w4, mi[kk + 2], sv);
            sv = fmaf(w5, up[kk + 2], sv);
            sv = fmaf(w6, up[kk + 1], sv);
            sv = fmaf(w7, up[kk],     sv);
            tv[kk] = 0.5f * mi[kk + 1] + 0.5f - 0.5f * sv;
            s += tv[kk];
            ss = fmaf(tv[kk], tv[kk], ss);
        }
        float4 t4 = {tv[0], tv[1], tv[2], tv[3]};
        *reinterpret_cast<float4*>(ob + (size_t)rr * W) = t4;
    }

    #pragma unroll
    for (int off = 32; off >= 1; off >>= 1) {
        s  += __shfl_down(s, off);
        ss += __shfl_down(ss, off);
    }
    __shared__ float2 wred[4];
    if (l == 0) wred[w] = make_float2(s, ss);
    __syncthreads();
    if (tid == 0) {
        float2 a0 = wred[0], a1 = wred[1], a2 = wred[2], a3 = wred[3];
        part[(size_t)b * RG + kg] = make_float2(a0.x + a1.x + a2.x + a3.x,
                                                a0.y + a1.y + a2.y + a3.y);
    }
}

__global__ __launch_bounds__(256)
void ltpe_stageB(float* __restrict__ out, const float2* __restrict__ part)
{
    const int b    = blockIdx.y;
    const int r    = blockIdx.x;
    const int tid  = threadIdx.x;
    const int lane = tid & 63;

    const float4* pp = reinterpret_cast<const float4*>(part + (size_t)b * RG);
    const float4 u = pp[tid];
    double s  = (double)u.x + (double)u.z;
    double ss = (double)u.y + (double)u.w;
    #pragma unroll
    for (int off = 32; off >= 1; off >>= 1) {
        s  += __shfl_down(s, off);
        ss += __shfl_down(ss, off);
    }
    __shared__ double red[8];
    __shared__ float2 mv;
    const int wv = tid >> 6;
    if (lane == 0) { red[wv] = s; red[4 + wv] = ss; }
    __syncthreads();
    if (tid == 0) {
        const double S  = red[0] + red[1] + red[2] + red[3];
        const double SS = red[4] + red[5] + red[6] + red[7];
        const double n    = (double)NPIX;
        const double mean = S / n;
        const double var  = SS / n - mean * mean;
        mv = make_float2((float)mean, (float)(1.0 / sqrt(var + 1e-5)));
    }
    __syncthreads();
    const float mean = mv.x, rstd = mv.y;

    const size_t base = (size_t)b * 3 * NPIX + (size_t)r * W + (tid << 2);
    const float4 t4 = *reinterpret_cast<const float4*>(out + base);
    float4 y;
    y.x = (t4.x - mean) * rstd;
    y.y = (t4.y - mean) * rstd;
    y.z = (t4.z - mean) * rstd;
    y.w = (t4.w - mean) * rstd;
    *reinterpret_cast<float4*>(out + base)            = y;
    *reinterpret_cast<float4*>(out + base + NPIX)     = y;
    *reinterpret_cast<float4*>(out + base + 2 * NPIX) = y;
}

extern "C" void kernel_launch(void* const* d_in, const int* in_sizes, int n_in,
                              void* d_out, int out_size, void* d_ws, size_t ws_size,
                              hipStream_t stream)
{
    const float* x = (const float*)d_in[0];
    float* out = (float*)d_out;
    float2* part = (float2*)d_ws;   // fused: 1024 float2; fallback: 4096 float2

    // Host-side occupancy query (no stream ops; deterministic every call).
    int nb = 0;
    hipError_t qe = hipOccupancyMaxActiveBlocksPerMultiprocessor(
        &nb, reinterpret_cast<const void*>(ltpe_fused), 256, 0);

    if (qe == hipSuccess && nb * 256 >= FGRID) {
        void* args[] = { (void*)&x, (void*)&out, (void*)&part };
        hipLaunchCooperativeKernel((void*)ltpe_fused, dim3(FGRID), dim3(256),
                                   args, 0, stream);
    } else {
        ltpe_stage1<<<dim3(RG, B), 256, 0, stream>>>(x, out, part);
        ltpe_stageB<<<dim3(H, B), 256, 0, stream>>>(out, part);
    }
}

// Round 8
// 50.894 us; speedup vs baseline: 1.2435x; 1.0051x over previous
//
#include <hip/hip_runtime.h>
#include <hip/hip_cooperative_groups.h>
#include <math.h>

namespace cg = cooperative_groups;

// x = (8, 3, 1024, 1024) f32, out = (8, 3, 1024, 1024) f32
constexpr int H = 1024, W = 1024, B = 8;
constexpr int NPIX = H * W;

// ---------------- fused cooperative path ----------------
constexpr int FR    = 16;              // rows per block
constexpr int GPB   = H / FR;          // 64 row-groups per image
constexpr int FGRID = B * GPB;         // 512 blocks = 2/CU on 256 CUs

__device__ __forceinline__ void gload16(const float* g, float* l) {
    __builtin_amdgcn_global_load_lds(
        (const __attribute__((address_space(1))) void*)g,
        (__attribute__((address_space(3))) void*)l, 16, 0, 0);
}
__device__ __forceinline__ float grayat(const float* __restrict__ xb, int r, int c) {
    const float* p = xb + (size_t)r * W + c;
    return 0.3f * p[0] + 0.59f * p[NPIX] + 0.11f * p[2 * NPIX];
}

// One fused kernel. Phase A: per-wave pipelined staging (5-slot LDS ring,
// counted vmcnt, no barriers) -> gray -> stencil -> t in 16 float4 regs +
// per-block partial. grid.sync. Phase B: butterfly-reduce 64 partials/image
// (identical in every lane), normalize regs, write 3 replicated channels.
__global__ __launch_bounds__(256, 2)
void ltpe_fused(const float* __restrict__ x, float* __restrict__ out,
                float2* __restrict__ part)
{
    __shared__ float lds[4][5][3][256];   // per-wave ring: 5 slots x 3 ch x 256 cols
    __shared__ float2 wred[4];

    const int blk  = blockIdx.x;
    const int b    = blk & 7;             // image pinned to XCD
    const int g    = blk >> 3;            // row-group 0..63
    const int r0   = g * FR;
    const int tid  = threadIdx.x;
    const int w    = tid >> 6;
    const int lane = tid & 63;
    const int c    = tid << 2;            // global column quad
    const float* xb = x + (size_t)b * 3 * NPIX;
    float (*ldsw)[3][256] = lds[w];       // this wave's private ring

    constexpr float w0 = 1.f/255.f,  w1 = 2.f/255.f,  w2 = 4.f/255.f,  w3 = 8.f/255.f,
                    w4 = 16.f/255.f, w5 = 32.f/255.f, w6 = 64.f/255.f, w7 = 128.f/255.f;

    // Prologue: edge-lane horizontal-halo gray values into registers, so the
    // steady-state loop has NO vmem other than global_load_lds (exact vmcnt).
    float pL[FR + 2], pR[FR + 2];
    #pragma unroll
    for (int i = 0; i < FR + 2; ++i) { pL[i] = 0.f; pR[i] = 0.f; }
    if (lane == 0 && c > 0) {
        #pragma unroll
        for (int i = 0; i < FR + 2; ++i) {
            const int rr = r0 - 1 + i;
            if ((unsigned)rr < (unsigned)H) pL[i] = grayat(xb, rr, c - 1);
        }
    }
    if (lane == 63 && c + 4 < W) {
        #pragma unroll
        for (int i = 0; i < FR + 2; ++i) {
            const int rr = r0 - 1 + i;
            if ((unsigned)rr < (unsigned)H) pR[i] = grayat(xb, rr, c + 4);
        }
    }
    __builtin_amdgcn_sched_barrier(0);    // keep patch loads fully before staging

    // Stage row-offset `off` (row r0-1+off, CLAMPED so every block issues the
    // same gload count; garbage rows are zeroed at gray time) into ring slot.
    auto stage = [&](int off, int slot) {
        int rr = r0 - 1 + off;
        rr = rr < 0 ? 0 : (rr > H - 1 ? H - 1 : rr);
        const float* gp = xb + (size_t)rr * W + (w << 8) + (lane << 2);
        gload16(gp,            &ldsw[slot][0][0]);
        gload16(gp + NPIX,     &ldsw[slot][1][0]);
        gload16(gp + 2*NPIX,   &ldsw[slot][2][0]);
    };

    // Gray (6-wide) for row-offset `off` from ring slot.
    auto grayc = [&](int off, int slot, float (&d)[6]) {
        const bool rok = (unsigned)(r0 - 1 + off) < (unsigned)H;
        const float4 a = *reinterpret_cast<const float4*>(&ldsw[slot][0][lane << 2]);
        const float4 e = *reinterpret_cast<const float4*>(&ldsw[slot][1][lane << 2]);
        const float4 f = *reinterpret_cast<const float4*>(&ldsw[slot][2][lane << 2]);
        float g1 = 0.3f*a.x + 0.59f*e.x + 0.11f*f.x;
        float g2 = 0.3f*a.y + 0.59f*e.y + 0.11f*f.y;
        float g3 = 0.3f*a.z + 0.59f*e.z + 0.11f*f.z;
        float g4 = 0.3f*a.w + 0.59f*e.w + 0.11f*f.w;
        float glv = __shfl_up(g4, 1);
        float grv = __shfl_down(g1, 1);
        if (lane == 0)  glv = pL[off];
        if (lane == 63) grv = pR[off];
        if (!rok) { g1 = g2 = g3 = g4 = glv = grv = 0.f; }   // zero-pad row
        d[0]=glv; d[1]=g1; d[2]=g2; d[3]=g3; d[4]=g4; d[5]=grv;
    };

    float gr6[3][6];
    float4 tq[FR];                        // un-normalized t, lives in VGPRs
    float s = 0.f, ss = 0.f;

    // Pipeline prologue: offsets 0..3 staged (12 gloads); wait oldest 6.
    stage(0, 0); stage(1, 1); stage(2, 2); stage(3, 3);
    asm volatile("s_waitcnt vmcnt(6)" ::: "memory");
    __builtin_amdgcn_sched_barrier(0);
    grayc(0, 0, gr6[0]);
    grayc(1, 1, gr6[1]);

    // Step I: issue offset I+4 (3 gloads), wait so offset I+2 is resident
    // (outstanding = offsets I+3, I+4 = 6), gray(I+2), stencil output row r0+I.
#define LTPE_STEP(I, WAITSTR)                                                  \
    {                                                                          \
        if ((I) + 4 <= FR + 1) stage((I) + 4, ((I) + 4) % 5);                  \
        asm volatile(WAITSTR ::: "memory");                                    \
        __builtin_amdgcn_sched_barrier(0);                                     \
        grayc((I) + 2, ((I) + 2) % 5, gr6[((I) + 2) % 3]);                     \
        const float (&up)[6] = gr6[(I) % 3];                                   \
        const float (&mi)[6] = gr6[((I) + 1) % 3];                             \
        const float (&dn)[6] = gr6[((I) + 2) % 3];                             \
        float tv[4];                                                           \
        _Pragma("unroll")                                                      \
        for (int kk = 0; kk < 4; ++kk) {                                       \
            float sv = w0 * mi[kk];                                            \
            sv = fmaf(w1, dn[kk],     sv);                                     \
            sv = fmaf(w2, dn[kk + 1], sv);                                     \
            sv = fmaf(w3, dn[kk + 2], sv);                                     \
            sv = fmaf(w4, mi[kk + 2], sv);                                     \
            sv = fmaf(w5, up[kk + 2], sv);                                     \
            sv = fmaf(w6, up[kk + 1], sv);                                     \
            sv = fmaf(w7, up[kk],     sv);                                     \
            tv[kk] = 0.5f * mi[kk + 1] + 0.5f - 0.5f * sv;                     \
            s += tv[kk];                                                       \
            ss = fmaf(tv[kk], tv[kk], ss);                                     \
        }                                                                      \
        tq[I] = make_float4(tv[0], tv[1], tv[2], tv[3]);                       \
    }

    LTPE_STEP(0,  "s_waitcnt vmcnt(6)")
    LTPE_STEP(1,  "s_waitcnt vmcnt(6)")
    LTPE_STEP(2,  "s_waitcnt vmcnt(6)")
    LTPE_STEP(3,  "s_waitcnt vmcnt(6)")
    LTPE_STEP(4,  "s_waitcnt vmcnt(6)")
    LTPE_STEP(5,  "s_waitcnt vmcnt(6)")
    LTPE_STEP(6,  "s_waitcnt vmcnt(6)")
    LTPE_STEP(7,  "s_waitcnt vmcnt(6)")
    LTPE_STEP(8,  "s_waitcnt vmcnt(6)")
    LTPE_STEP(9,  "s_waitcnt vmcnt(6)")
    LTPE_STEP(10, "s_waitcnt vmcnt(6)")
    LTPE_STEP(11, "s_waitcnt vmcnt(6)")
    LTPE_STEP(12, "s_waitcnt vmcnt(6)")
    LTPE_STEP(13, "s_waitcnt vmcnt(6)")
    LTPE_STEP(14, "s_waitcnt vmcnt(3)")
    LTPE_STEP(15, "s_waitcnt vmcnt(0)")
#undef LTPE_STEP

    // Block reduce -> one fp32 partial pair per block.
    #pragma unroll
    for (int off = 32; off >= 1; off >>= 1) {
        s  += __shfl_down(s, off);
        ss += __shfl_down(ss, off);
    }
    if (lane == 0) wred[w] = make_float2(s, ss);
    __syncthreads();
    if (tid == 0) {
        float2 a0 = wred[0], a1 = wred[1], a2 = wred[2], a3 = wred[3];
        part[(size_t)b * GPB + g] = make_float2(a0.x + a1.x + a2.x + a3.x,
                                                a0.y + a1.y + a2.y + a3.y);
    }

    cg::this_grid().sync();

    // Phase B: butterfly-reduce the image's 64 partials (one per lane) in double.
    const float2 pv = part[(size_t)b * GPB + lane];
    double ds = (double)pv.x, dss = (double)pv.y;
    #pragma unroll
    for (int o = 1; o <= 32; o <<= 1) {
        ds  += __shfl_xor(ds, o);
        dss += __shfl_xor(dss, o);
    }
    const double n     = (double)NPIX;
    const double dmean = ds / n;
    const double dvar  = dss / n - dmean * dmean;
    const float mean = (float)dmean;
    const float rstd = (float)(1.0 / sqrt(dvar + 1e-5));

    float* ob = out + (size_t)b * 3 * NPIX + (size_t)r0 * W + c;
    #pragma unroll
    for (int i = 0; i < FR; ++i) {
        const float4 t4 = tq[i];
        float4 y;
        y.x = (t4.x - mean) * rstd;
        y.y = (t4.y - mean) * rstd;
        y.z = (t4.z - mean) * rstd;
        y.w = (t4.w - mean) * rstd;
        float* p = ob + (size_t)i * W;
        *reinterpret_cast<float4*>(p)            = y;
        *reinterpret_cast<float4*>(p + NPIX)     = y;
        *reinterpret_cast<float4*>(p + 2 * NPIX) = y;
    }
}

// ---------------- fallback: proven round-6 two-kernel pipeline ----------------
constexpr int ROWS = 2;
constexpr int RG   = H / ROWS;          // 512

__global__ __launch_bounds__(256)
void ltpe_stage1(const float* __restrict__ x, float* __restrict__ out,
                 float2* __restrict__ part)
{
    __shared__ float lds[4][3][W];                // 48 KiB -> 3 blocks/CU
    const int b   = blockIdx.y;
    const int k   = blockIdx.x;
    const int kg  = ((k & 7) << 6) | (k >> 3);    // XCD-chunked bijective swizzle
    const int r0  = kg * ROWS;
    const int tid = threadIdx.x;
    const int w   = tid >> 6;
    const int l   = tid & 63;
    const int c   = tid << 2;
    const float* xb = x + (size_t)b * 3 * NPIX;

    #pragma unroll
    for (int s = 0; s < 4; ++s) {
        const int rr = r0 - 1 + s;
        if ((unsigned)rr < (unsigned)H) {
            #pragma unroll
            for (int ch = 0; ch < 3; ++ch) {
                const float* gp = xb + (size_t)ch * NPIX + (size_t)rr * W + (w << 8) + (l << 2);
                gload16(gp, &lds[s][ch][w << 8]);
            }
        } else {
            const float4 z = make_float4(0.f, 0.f, 0.f, 0.f);
            #pragma unroll
            for (int ch = 0; ch < 3; ++ch)
                *reinterpret_cast<float4*>(&lds[s][ch][c]) = z;
        }
    }
    __syncthreads();

    const int ql = (tid == 0)   ? 0   : tid - 1;
    const int qr = (tid == 255) ? 255 : tid + 1;
    float g6[4][6];
    #pragma unroll
    for (int s = 0; s < 4; ++s) {
        const float4 o0 = *reinterpret_cast<const float4*>(&lds[s][0][c]);
        const float4 o1 = *reinterpret_cast<const float4*>(&lds[s][1][c]);
        const float4 o2 = *reinterpret_cast<const float4*>(&lds[s][2][c]);
        const float4 l0 = *reinterpret_cast<const float4*>(&lds[s][0][ql << 2]);
        const float4 l1 = *reinterpret_cast<const float4*>(&lds[s][1][ql << 2]);
        const float4 l2 = *reinterpret_cast<const float4*>(&lds[s][2][ql << 2]);
        const float4 rq0 = *reinterpret_cast<const float4*>(&lds[s][0][qr << 2]);
        const float4 rq1 = *reinterpret_cast<const float4*>(&lds[s][1][qr << 2]);
        const float4 rq2 = *reinterpret_cast<const float4*>(&lds[s][2][qr << 2]);
        g6[s][1] = 0.3f * o0.x + 0.59f * o1.x + 0.11f * o2.x;
        g6[s][2] = 0.3f * o0.y + 0.59f * o1.y + 0.11f * o2.y;
        g6[s][3] = 0.3f * o0.z + 0.59f * o1.z + 0.11f * o2.z;
        g6[s][4] = 0.3f * o0.w + 0.59f * o1.w + 0.11f * o2.w;
        g6[s][0] = (tid == 0)   ? 0.f : 0.3f * l0.w  + 0.59f * l1.w  + 0.11f * l2.w;
        g6[s][5] = (tid == 255) ? 0.f : 0.3f * rq0.x + 0.59f * rq1.x + 0.11f * rq2.x;
    }

    constexpr float w0 = 1.f/255.f,  w1 = 2.f/255.f,  w2 = 4.f/255.f,  w3 = 8.f/255.f,
                    w4 = 16.f/255.f, w5 = 32.f/255.f, w6 = 64.f/255.f, w7 = 128.f/255.f;
    float s = 0.f, ss = 0.f;
    float* ob = out + (size_t)b * 3 * NPIX + (size_t)r0 * W + c;
    #pragma unroll
    for (int rr = 0; rr < ROWS; ++rr) {
        const float (&up)[6] = g6[rr];
        const float (&mi)[6] = g6[rr + 1];
        const float (&dn)[6] = g6[rr + 2];
        float tv[4];
        #pragma unroll
        for (int kk = 0; kk < 4; ++kk) {
            float sv = w0 * mi[kk];
            sv = fmaf(w1, dn[kk],     sv);
            sv = fmaf(w2, dn[kk + 1], sv);
            sv = fmaf(w3, dn[kk + 2], sv);
            sv = fmaf(w4, mi[kk + 2], sv);
            sv = fmaf(w5, up[kk + 2], sv);
            sv = fmaf(w6, up[kk + 1], sv);
            sv = fmaf(w7, up[kk],     sv);
            tv[kk] = 0.5f * mi[kk + 1] + 0.5f - 0.5f * sv;
            s += tv[kk];
            ss = fmaf(tv[kk], tv[kk], ss);
        }
        float4 t4 = {tv[0], tv[1], tv[2], tv[3]};
        *reinterpret_cast<float4*>(ob + (size_t)rr * W) = t4;
    }

    #pragma unroll
    for (int off = 32; off >= 1; off >>= 1) {
        s  += __shfl_down(s, off);
        ss += __shfl_down(ss, off);
    }
    __shared__ float2 wred[4];
    if (l == 0) wred[w] = make_float2(s, ss);
    __syncthreads();
    if (tid == 0) {
        float2 a0 = wred[0], a1 = wred[1], a2 = wred[2], a3 = wred[3];
        part[(size_t)b * RG + kg] = make_float2(a0.x + a1.x + a2.x + a3.x,
                                                a0.y + a1.y + a2.y + a3.y);
    }
}

__global__ __launch_bounds__(256)
void ltpe_stageB(float* __restrict__ out, const float2* __restrict__ part)
{
    const int b    = blockIdx.y;
    const int r    = blockIdx.x;
    const int tid  = threadIdx.x;
    const int lane = tid & 63;

    const float4* pp = reinterpret_cast<const float4*>(part + (size_t)b * RG);
    const float4 u = pp[tid];
    double s  = (double)u.x + (double)u.z;
    double ss = (double)u.y + (double)u.w;
    #pragma unroll
    for (int off = 32; off >= 1; off >>= 1) {
        s  += __shfl_down(s, off);
        ss += __shfl_down(ss, off);
    }
    __shared__ double red[8];
    __shared__ float2 mv;
    const int wv = tid >> 6;
    if (lane == 0) { red[wv] = s; red[4 + wv] = ss; }
    __syncthreads();
    if (tid == 0) {
        const double S  = red[0] + red[1] + red[2] + red[3];
        const double SS = red[4] + red[5] + red[6] + red[7];
        const double n    = (double)NPIX;
        const double mean = S / n;
        const double var  = SS / n - mean * mean;
        mv = make_float2((float)mean, (float)(1.0 / sqrt(var + 1e-5)));
    }
    __syncthreads();
    const float mean = mv.x, rstd = mv.y;

    const size_t base = (size_t)b * 3 * NPIX + (size_t)r * W + (tid << 2);
    const float4 t4 = *reinterpret_cast<const float4*>(out + base);
    float4 y;
    y.x = (t4.x - mean) * rstd;
    y.y = (t4.y - mean) * rstd;
    y.z = (t4.z - mean) * rstd;
    y.w = (t4.w - mean) * rstd;
    *reinterpret_cast<float4*>(out + base)            = y;
    *reinterpret_cast<float4*>(out + base + NPIX)     = y;
    *reinterpret_cast<float4*>(out + base + 2 * NPIX) = y;
}

extern "C" void kernel_launch(void* const* d_in, const int* in_sizes, int n_in,
                              void* d_out, int out_size, void* d_ws, size_t ws_size,
                              hipStream_t stream)
{
    const float* x = (const float*)d_in[0];
    float* out = (float*)d_out;
    float2* part = (float2*)d_ws;   // fused: 512 float2; fallback: 4096 float2

    int nb = 0;
    hipError_t qe = hipOccupancyMaxActiveBlocksPerMultiprocessor(
        &nb, reinterpret_cast<const void*>(ltpe_fused), 256, 0);

    if (qe == hipSuccess && nb * 256 >= FGRID) {
        void* args[] = { (void*)&x, (void*)&out, (void*)&part };
        hipLaunchCooperativeKernel((void*)ltpe_fused, dim3(FGRID), dim3(256),
                                   args, 0, stream);
    } else {
        ltpe_stage1<<<dim3(RG, B), 256, 0, stream>>>(x, out, part);
        ltpe_stageB<<<dim3(H, B), 256, 0, stream>>>(out, part);
    }
}